// Round 10
// baseline (313.560 us; speedup 1.0000x reference)
//
#include <hip/hip_runtime.h>
#include <cstdint>

// ---------------------------------------------------------------------------
// Types
// ---------------------------------------------------------------------------
typedef unsigned short u16;
typedef __bf16 bf16x8 __attribute__((ext_vector_type(8)));
typedef float  f32x4  __attribute__((ext_vector_type(4)));

// Problem constants
#define BB 4
#define NX 2048
#define NY 2048
#define DIM 1024
#define IN_DIM 1024
#define NH 16
#define HD 64
// SCALE * log2(e) — folded into the q projection epilogue
#define SL (0.125f * 1.4426950408889634f)

#if __has_builtin(__builtin_amdgcn_exp2f)
#define EXP2(x) __builtin_amdgcn_exp2f(x)
#else
#define EXP2(x) exp2f(x)
#endif

#if __has_builtin(__builtin_amdgcn_cvt_pk_bf16_f32)
#define HAS_PKBF16 1
#else
#define HAS_PKBF16 0
#endif

// f32 -> bf16 round-to-nearest-even
__device__ __forceinline__ u16 f2bf(float f) {
    unsigned int u = __builtin_bit_cast(unsigned int, f);
    unsigned int r = (u + 0x7FFFu + ((u >> 16) & 1u)) >> 16;
    return (u16)r;
}

// pack two f32 -> packed bf16x2 dword (RNE)
__device__ __forceinline__ unsigned int pk2(float a, float b) {
#if HAS_PKBF16
    auto t = __builtin_amdgcn_cvt_pk_bf16_f32(a, b);
    return __builtin_bit_cast(unsigned int, t);
#else
    return (unsigned int)f2bf(a) | ((unsigned int)f2bf(b) << 16);
#endif
}

// pack two ALREADY-TRUNCATED f32 -> bf16x2 via one v_perm_b32
__device__ __forceinline__ unsigned int pk2t(float a, float b) {
    return __builtin_amdgcn_perm(__builtin_bit_cast(unsigned int, b),
                                 __builtin_bit_cast(unsigned int, a),
                                 0x07060302u);
}

// truncate f32 to bf16-representable value (1 v_and)
__device__ __forceinline__ float truncbf(float f) {
    return __builtin_bit_cast(float,
        __builtin_bit_cast(unsigned int, f) & 0xFFFF0000u);
}

// async global -> LDS, 16B per lane (wave-uniform LDS base + lane*16)
__device__ __forceinline__ void gl_lds16(const u16* g, u16* l) {
    __builtin_amdgcn_global_load_lds(
        (const __attribute__((address_space(1))) unsigned int*)g,
        (__attribute__((address_space(3))) unsigned int*)l, 16, 0, 0);
}

// ---------------------------------------------------------------------------
// prep: f32->bf16 convert of x,y  +  all three weight transposes, one launch
// grid: 16384 cvt blocks + 4096 transpose blocks = 20480
// ---------------------------------------------------------------------------
__global__ __launch_bounds__(256) void prep(const float* __restrict__ x,
                                            const float* __restrict__ y,
                                            const float* __restrict__ Wq,
                                            const float* __restrict__ Wkv,
                                            const float* __restrict__ Wo,
                                            u16* __restrict__ xb,
                                            u16* __restrict__ yb,
                                            u16* __restrict__ WqT,
                                            u16* __restrict__ WkvT,
                                            u16* __restrict__ WoT) {
    const int bx = blockIdx.x;
    if (bx < 16384) {
        const float* in = (bx < 8192) ? x : y;
        u16* out = (bx < 8192) ? xb : yb;
        int i = (bx & 8191) * 256 + threadIdx.x;
        float4 v = ((const float4*)in)[i];
        ushort4 o;
        o.x = f2bf(v.x); o.y = f2bf(v.y); o.z = f2bf(v.z); o.w = f2bf(v.w);
        ((ushort4*)out)[i] = o;
    } else {
        __shared__ u16 t[32 * 33];
        int id = bx - 16384;                 // 0..4095
        int nx = id & 127;
        const int k0 = (id >> 7) * 32;
        const float* W; u16* Wt; int N;
        if (nx < 32)      { W = Wq;  Wt = WqT;  N = 1024; }
        else if (nx < 96) { W = Wkv; Wt = WkvT; N = 2048; nx -= 32; }
        else              { W = Wo;  Wt = WoT;  N = 1024; nx -= 96; }
        const int K = 1024;
        const int tid = threadIdx.x;
        const int col = tid & 31, rw = tid >> 5;
        const int n0 = nx * 32;
#pragma unroll
        for (int i = 0; i < 4; i++) {
            int k = rw + i * 8;
            float v = W[(size_t)(k0 + k) * N + n0 + col];
            t[col * 33 + k] = f2bf(v);
        }
        __syncthreads();
#pragma unroll
        for (int i = 0; i < 4; i++) {
            int n = rw + i * 8;
            Wt[(size_t)(n0 + n) * K + k0 + col] = t[n * 33 + col];
        }
    }
}

// ---------------------------------------------------------------------------
// GEMM accumulate core, BK=64, XOR-swizzled async staging.
// Tile 128 x TN. acc = A[M][K] * Bt[N][K]^T for this block's tile.
// ---------------------------------------------------------------------------
template <int TN>
__device__ __forceinline__ void gemm_accum(u16* As, u16* Bs,
                                           const u16* __restrict__ A,
                                           const u16* __restrict__ Bt,
                                           int K, int m0, int n0,
                                           f32x4 (&acc)[4][TN / 32]) {
    constexpr int NJ = TN / 32;
    const int tid = threadIdx.x;
    const int wave = tid >> 6, lane = tid & 63;
    const int ml = lane & 15, qd = lane >> 4;
    const int mlo = ml & 7;
    const int wm = (wave >> 1) * 64, wn = (wave & 1) * (TN / 2);

#pragma unroll
    for (int i = 0; i < 4; i++)
#pragma unroll
        for (int j = 0; j < NJ; j++)
#pragma unroll
            for (int e = 0; e < 4; e++) acc[i][j][e] = 0.0f;

    const int r0 = tid >> 3;
    const int swz = (tid & 7) ^ (r0 & 7);
    const u16* Ap = A + (size_t)(m0 + r0) * K + swz * 8;
    const u16* Bp = Bt + (size_t)(n0 + r0) * K + swz * 8;

    for (int k0 = 0; k0 < K; k0 += 64) {
        __syncthreads();
#pragma unroll
        for (int i = 0; i < 4; i++)
            gl_lds16(Ap + (size_t)(i * 32) * K + k0, &As[(i * 256 + wave * 64) * 8]);
#pragma unroll
        for (int i = 0; i < TN / 32; i++)
            gl_lds16(Bp + (size_t)(i * 32) * K + k0, &Bs[(i * 256 + wave * 64) * 8]);
        __syncthreads();

#pragma unroll
        for (int s = 0; s < 2; s++) {
            bf16x8 af[4], bfr[NJ];
#pragma unroll
            for (int i = 0; i < 4; i++)
                af[i] = *(const bf16x8*)&As[(wm + i * 16 + ml) * 64 + (((s * 4 + qd) ^ mlo) * 8)];
#pragma unroll
            for (int j = 0; j < NJ; j++)
                bfr[j] = *(const bf16x8*)&Bs[(wn + j * 16 + ml) * 64 + (((s * 4 + qd) ^ mlo) * 8)];
#pragma unroll
            for (int i = 0; i < 4; i++)
#pragma unroll
                for (int j = 0; j < NJ; j++)
                    acc[i][j] = __builtin_amdgcn_mfma_f32_16x16x32_bf16(af[i], bfr[j], acc[i][j], 0, 0, 0);
        }
    }
}

// ---------------------------------------------------------------------------
// Fused q + kv projection.  grid (24, 64):
//   x<8         : q = SL * x @ Wq           -> qb  [8192][1024] bf16
//   8<=x<16     : k = y @ Wkv[:, :1024]     -> kb  [8192][1024] bf16
//   16<=x<24    : v = y @ Wkv[:, 1024:]     -> vT  [bh][64][2048] bf16 via an
//                 LDS transpose (coalesced 256-B row stores), y interleaved
//                 within 32-groups (logical 16a+4q+j -> phys 8q+4a+j) so
//                 flash reads one b128 per PV fragment.
// lb(256,4): cap regs at 128 -> 4 blocks/CU (acc 64 + frags 32 + addr fits).
// ---------------------------------------------------------------------------
__global__ __launch_bounds__(256, 4) void gemm_proj(const u16* __restrict__ xb,
                                                    const u16* __restrict__ yb,
                                                    const u16* __restrict__ WqT,
                                                    const u16* __restrict__ WkvT,
                                                    u16* __restrict__ qb,
                                                    u16* __restrict__ kb,
                                                    u16* __restrict__ vT) {
    __shared__ u16 smem[2 * 128 * 64];       // As | Bs; reused as 128x128 buf
    u16* As = smem;
    u16* Bs = smem + 128 * 64;
    const int tid = threadIdx.x;
    const int wave = tid >> 6, lane = tid & 63;
    const int ml = lane & 15, qd = lane >> 4;
    const int m0 = blockIdx.y * 128;
    const bool isq = blockIdx.x < 8;
    const int n0 = (isq ? blockIdx.x : blockIdx.x - 8) * 128;   // 0..1023 / 0..2047

    f32x4 acc[4][4];
    if (isq) gemm_accum<128>(As, Bs, xb, WqT, 1024, m0, n0, acc);
    else     gemm_accum<128>(As, Bs, yb, WkvT, 1024, m0, n0, acc);

    const int wm = (wave >> 1) * 64, wn = (wave & 1) * 64;

    if (isq || n0 < 1024) {
        // q (scaled) or K half: bf16, row-major stride 1024
        u16* C = isq ? qb : kb;
        const float oscale = isq ? SL : 1.0f;
#pragma unroll
        for (int i = 0; i < 4; i++)
#pragma unroll
            for (int j = 0; j < 4; j++)
#pragma unroll
                for (int r = 0; r < 4; r++) {
                    int row = m0 + wm + i * 16 + qd * 4 + r;
                    int col = n0 + wn + j * 16 + ml;
                    C[(size_t)row * 1024 + col] = f2bf(acc[i][j][r] * oscale);
                }
    } else {
        // V half: LDS transpose -> coalesced vT[bh][d][y_phys] stores
        __syncthreads();                     // all waves done reading As/Bs
#pragma unroll
        for (int i = 0; i < 4; i++) {
            const int yphys = ((wm + i * 16) >> 5) * 32 + 8 * qd + 4 * (i & 1);
#pragma unroll
            for (int j = 0; j < 4; j++) {
                const int dl = wn + j * 16 + ml;        // 0..127
                uint2 val;
                val.x = pk2(acc[i][j][0], acc[i][j][1]);
                val.y = pk2(acc[i][j][2], acc[i][j][3]);
                *(uint2*)&smem[dl * 128 + yphys] = val;
            }
        }
        __syncthreads();
        // copy out: 2 threads per d-row, 128 B each (contiguous)
        const int b = m0 >> 11;              // batch
        const int yy0 = m0 & 2047;           // y base within batch
        const int dl = tid >> 1, half = tid & 1;
        const int dg = (n0 - 1024) + dl;     // global d: 0..1023
        const int h = dg >> 6, dd = dg & 63;
        u16* dst = &vT[((size_t)((b * NH + h) * HD + dd)) * NY + yy0 + half * 64];
        const u16* src = &smem[dl * 128 + half * 64];
#pragma unroll
        for (int c = 0; c < 8; c++)
            *(uint4*)(dst + c * 8) = *(const uint4*)(src + c * 8);
    }
}

// Output projection: grid (16, 64) = 1024 blocks, 128x64 tiles, f32 out.
__global__ __launch_bounds__(256, 4) void gemm_o(const u16* __restrict__ A,
                                                 const u16* __restrict__ Bt,
                                                 float* __restrict__ C) {
    __shared__ u16 As[128 * 64];
    __shared__ u16 Bs[64 * 64];
    const int tid = threadIdx.x;
    const int wave = tid >> 6, lane = tid & 63;
    const int ml = lane & 15, qd = lane >> 4;
    const int m0 = blockIdx.y * 128, n0 = blockIdx.x * 64;

    f32x4 acc[4][2];
    gemm_accum<64>(As, Bs, A, Bt, 1024, m0, n0, acc);

    const int wm = (wave >> 1) * 64, wn = (wave & 1) * 32;
#pragma unroll
    for (int i = 0; i < 4; i++)
#pragma unroll
        for (int j = 0; j < 2; j++)
#pragma unroll
            for (int r = 0; r < 4; r++) {
                int row = m0 + wm + i * 16 + qd * 4 + r;
                int col = n0 + wn + j * 16 + ml;
                C[(size_t)row * 1024 + col] = acc[i][j][r];
            }
}

// ---------------------------------------------------------------------------
// Flash attention. BM=128, grid 1024 = exactly 4 blocks/CU at lb(256,4).
// XCD-aware bid swizzle (resident blocks share 8 bh -> K/V L2-resident).
// Transposed scheme, ping-pong dbuf unrolled, no-max softmax (SL in q),
// lane-private l, P packed in registers. V fragment ds_reads HOISTED before
// the exp2 burst so LDS latency hides under VALU work.
//   S^T = K Q'^T   via mfma(A=K, B=Q')   -> lane col = q, rows = keys
//   O^T += V^T P^T via permuted-k mfma   (P never leaves registers)
// ---------------------------------------------------------------------------
__global__ __launch_bounds__(256, 4) void flash_attn(const u16* __restrict__ qg,
                                                     const u16* __restrict__ kg,
                                                     const u16* __restrict__ vTg,
                                                     u16* __restrict__ rg) {
    __shared__ u16 Kt[2][64 * 64];
    __shared__ u16 Vt[2][64 * 64];
    const int tid = threadIdx.x, wave = tid >> 6, lane = tid & 63;
    const int ml = lane & 15, qd = lane >> 4;
    // XCD swizzle: assume xcd = bid % 8 round-robin; give each XCD 8 bh values
    const int bid = blockIdx.x + 16 * blockIdx.y;    // 0..1023
    const int slot = bid >> 3;
    const int bh = (bid & 7) + 8 * (slot & 7);       // 0..63
    const int xt = slot >> 3;                        // 0..15
    const int b = bh >> 4, h = bh & 15;
    const int mlo = ml & 7;

    // Q fragments (B-operand), pre-scaled by SCALE*log2e at projection time
    bf16x8 aq[2][2];
    {
        size_t qbase = ((size_t)(b * NX + xt * 128 + wave * 32)) * DIM + h * HD;
#pragma unroll
        for (int mt = 0; mt < 2; mt++)
#pragma unroll
            for (int s = 0; s < 2; s++)
                aq[mt][s] = *(const bf16x8*)&qg[qbase + (size_t)(mt * 16 + ml) * DIM + s * 32 + qd * 8];
    }

    // loop-invariant LDS read offsets (bytes); K and V share the same form
    int ka[2];
#pragma unroll
    for (int s = 0; s < 2; s++) ka[s] = ml * 128 + (((s * 4 + qd) ^ mlo) << 4);
    const char* Kb = (const char*)&Kt[0][0];
    const char* Vb = (const char*)&Vt[0][0];

    // staging: 2 async 16B loads per wave per operand per tile, XOR-swizzled
    const int rloc = lane >> 3;
    const int swz = (lane & 7) ^ rloc;
    const u16* ksrc[2];
    const u16* vsrc[2];
#pragma unroll
    for (int e = 0; e < 2; e++) {
        int row = (wave * 2 + e) * 8 + rloc;
        ksrc[e] = kg + ((size_t)(b * NY + row)) * 1024 + h * HD + swz * 8;
        vsrc[e] = vTg + ((size_t)(bh * HD + row)) * NY + swz * 8;
    }
    const size_t KSTRIDE = (size_t)64 * 1024;
    const size_t VSTRIDE = 64;

    f32x4 o[2][4];
    f32x4 li4[2];
#pragma unroll
    for (int mt = 0; mt < 2; mt++) {
#pragma unroll
        for (int e = 0; e < 4; e++) li4[mt][e] = 0.0f;
#pragma unroll
        for (int dt = 0; dt < 4; dt++)
#pragma unroll
            for (int e = 0; e < 4; e++) o[mt][dt][e] = 0.0f;
    }
    const f32x4 fz = {0.0f, 0.0f, 0.0f, 0.0f};

    // prefetch tile 0 into buf 0, bump srcs
#pragma unroll
    for (int e = 0; e < 2; e++) { gl_lds16(ksrc[e], &Kt[0][(wave * 2 + e) * 512]); ksrc[e] += KSTRIDE; }
#pragma unroll
    for (int e = 0; e < 2; e++) { gl_lds16(vsrc[e], &Vt[0][(wave * 2 + e) * 512]); vsrc[e] += VSTRIDE; }

    for (int it = 0; it < NY / 64; it += 2) {
#pragma unroll
        for (int half = 0; half < 2; ++half) {
            __syncthreads();                 // tile (it+half) landed; other buf free
            if (it + half + 1 < NY / 64) {   // prefetch next into other buf
#pragma unroll
                for (int e = 0; e < 2; e++) { gl_lds16(ksrc[e], &Kt[half ^ 1][(wave * 2 + e) * 512]); ksrc[e] += KSTRIDE; }
#pragma unroll
                for (int e = 0; e < 2; e++) { gl_lds16(vsrc[e], &Vt[half ^ 1][(wave * 2 + e) * 512]); vsrc[e] += VSTRIDE; }
            }

            // ---- S^T = K Q'^T ----
            f32x4 sc[2][4];
#pragma unroll
            for (int t = 0; t < 4; t++) {
                bf16x8 kf0 = *(const bf16x8*)(Kb + (half * 8192 + t * 2048) + ka[0]);
                bf16x8 kf1 = *(const bf16x8*)(Kb + (half * 8192 + t * 2048) + ka[1]);
                sc[0][t] = __builtin_amdgcn_mfma_f32_16x16x32_bf16(kf0, aq[0][0], fz, 0, 0, 0);
                sc[1][t] = __builtin_amdgcn_mfma_f32_16x16x32_bf16(kf0, aq[1][0], fz, 0, 0, 0);
                sc[0][t] = __builtin_amdgcn_mfma_f32_16x16x32_bf16(kf1, aq[0][1], sc[0][t], 0, 0, 0);
                sc[1][t] = __builtin_amdgcn_mfma_f32_16x16x32_bf16(kf1, aq[1][1], sc[1][t], 0, 0, 0);
            }

            // ---- hoisted V fragment reads: LDS latency hides under exp2 ----
            bf16x8 vv[2][4];
#pragma unroll
            for (int t2 = 0; t2 < 2; t2++)
#pragma unroll
                for (int dt = 0; dt < 4; dt++)
                    vv[t2][dt] = *(const bf16x8*)(Vb + (half * 8192 + dt * 2048) + ka[t2]);

            // ---- softmax (no max) + pack P^T into PV quads ----
            uint4 pb[2][2];                  // [mt][t2]
#pragma unroll
            for (int mt = 0; mt < 2; mt++) {
#pragma unroll
                for (int t = 0; t < 4; t++)
#pragma unroll
                    for (int r = 0; r < 4; r++) sc[mt][t][r] = EXP2(sc[mt][t][r]);
#if HAS_PKBF16
                li4[mt] += (sc[mt][0] + sc[mt][1]) + (sc[mt][2] + sc[mt][3]);
#pragma unroll
                for (int t2 = 0; t2 < 2; t2++) {
                    pb[mt][t2].x = pk2(sc[mt][2 * t2][0], sc[mt][2 * t2][1]);
                    pb[mt][t2].y = pk2(sc[mt][2 * t2][2], sc[mt][2 * t2][3]);
                    pb[mt][t2].z = pk2(sc[mt][2 * t2 + 1][0], sc[mt][2 * t2 + 1][1]);
                    pb[mt][t2].w = pk2(sc[mt][2 * t2 + 1][2], sc[mt][2 * t2 + 1][3]);
                }
#else
#pragma unroll
                for (int t = 0; t < 4; t++)
#pragma unroll
                    for (int r = 0; r < 4; r++) sc[mt][t][r] = truncbf(sc[mt][t][r]);
                li4[mt] += (sc[mt][0] + sc[mt][1]) + (sc[mt][2] + sc[mt][3]);
#pragma unroll
                for (int t2 = 0; t2 < 2; t2++) {
                    pb[mt][t2].x = pk2t(sc[mt][2 * t2][0], sc[mt][2 * t2][1]);
                    pb[mt][t2].y = pk2t(sc[mt][2 * t2][2], sc[mt][2 * t2][3]);
                    pb[mt][t2].z = pk2t(sc[mt][2 * t2 + 1][0], sc[mt][2 * t2 + 1][1]);
                    pb[mt][t2].w = pk2t(sc[mt][2 * t2 + 1][2], sc[mt][2 * t2 + 1][3]);
                }
#endif
            }

            // ---- O^T += V^T P^T (permuted-k, V already in registers) ----
#pragma unroll
            for (int t2 = 0; t2 < 2; t2++) {
                bf16x8 p0 = __builtin_bit_cast(bf16x8, pb[0][t2]);
                bf16x8 p1 = __builtin_bit_cast(bf16x8, pb[1][t2]);
#pragma unroll
                for (int dt = 0; dt < 4; dt++) {
                    o[0][dt] = __builtin_amdgcn_mfma_f32_16x16x32_bf16(vv[t2][dt], p0, o[0][dt], 0, 0, 0);
                    o[1][dt] = __builtin_amdgcn_mfma_f32_16x16x32_bf16(vv[t2][dt], p1, o[1][dt], 0, 0, 0);
                }
            }
        }
    }

    // epilogue: reduce l, lane holds O[q=mt*16+ml][d=dt*16+qd*4+r]
#pragma unroll
    for (int mt = 0; mt < 2; mt++) {
        float l = (li4[mt][0] + li4[mt][1]) + (li4[mt][2] + li4[mt][3]);
        l += __shfl_xor(l, 16);
        l += __shfl_xor(l, 32);
        float inv = 1.0f / l;
        size_t row = (size_t)(b * NX + xt * 128 + wave * 32 + mt * 16 + ml);
#pragma unroll
        for (int dt = 0; dt < 4; dt++) {
            uint2 val;
            val.x = pk2(o[mt][dt][0] * inv, o[mt][dt][1] * inv);
            val.y = pk2(o[mt][dt][2] * inv, o[mt][dt][3] * inv);
            *(uint2*)&rg[row * DIM + h * HD + dt * 16 + qd * 4] = val;
        }
    }
}

// ---------------------------------------------------------------------------
// Launch
// ---------------------------------------------------------------------------
extern "C" void kernel_launch(void* const* d_in, const int* in_sizes, int n_in,
                              void* d_out, int out_size, void* d_ws, size_t ws_size,
                              hipStream_t stream) {
    const float* x   = (const float*)d_in[0];
    const float* y   = (const float*)d_in[1];
    const float* Wq  = (const float*)d_in[2];
    const float* Wkv = (const float*)d_in[3];
    const float* Wo  = (const float*)d_in[4];

    char* ws = (char*)d_ws;
    u16* xb   = (u16*)(ws + 0);                 // 16.8 MB
    u16* yb   = (u16*)(ws + 16777216);          // 16.8 MB
    u16* WqT  = (u16*)(ws + 33554432);          //  2.1 MB
    u16* WkvT = (u16*)(ws + 35651584);          //  4.2 MB
    u16* WoT  = (u16*)(ws + 39845888);          //  2.1 MB
    u16* qb   = (u16*)(ws + 41943040);          // 16.8 MB
    u16* kb   = (u16*)(ws + 58720256);          // 16.8 MB (K only)
    u16* vTb  = (u16*)(ws + 92274688);          // 16.8 MB
    u16* rb   = (u16*)(ws + 109051904);         // 16.8 MB

    prep<<<20480, 256, 0, stream>>>(x, y, Wq, Wkv, Wo, xb, yb, WqT, WkvT, WoT);

    // fused q (SL folded) + K + V^T-direct projections
    gemm_proj<<<dim3(24, 64), 256, 0, stream>>>(xb, yb, WqT, WkvT, qb, kb, vTb);

    flash_attn<<<dim3(16, 64), 256, 0, stream>>>(qb, kb, vTb, rb);

    gemm_o<<<dim3(16, 64), 256, 0, stream>>>(rb, WoT, (float*)d_out);
}